// Round 1
// baseline (678.635 us; speedup 1.0000x reference)
//
#include <hip/hip_runtime.h>

// Problem constants (from reference): x[B,C,H,W] fp32, perm[B,G*G] int32, G=4.
constexpr int B = 16, C = 128, H = 224, W = 224, G = 4;
constexpr int BH = H / G;       // 56 rows per block
constexpr int BW4 = (W / G) / 4; // 14 float4 per block row
constexpr int W4 = W / 4;       // 56 float4 per image row
constexpr int TOTAL4 = B * C * H * W4; // 25,690,112 float4 elements

// Scatter: input block (si,sj) of batch b goes to output block position
// p = perm[b, si*G + sj]  ->  (oi,oj) = (p/G, p%G).
__global__ __launch_bounds__(256) void block_shuffle_kernel(
    const float4* __restrict__ x, const int* __restrict__ perm,
    float4* __restrict__ out) {
  int idx = blockIdx.x * 256 + threadIdx.x;
  if (idx >= TOTAL4) return;

  int w4 = idx % W4;        // float4 column within row [0,56)
  int t  = idx / W4;        // (b*C + c)*H + h
  int h  = t % H;
  int bc = t / H;           // b*C + c
  int b  = bc / C;

  int si = h / BH;          // source block row   [0,4)
  int y  = h - si * BH;     // row within block   [0,56)
  int sj = w4 / BW4;        // source block col   [0,4)
  int x4 = w4 - sj * BW4;   // float4 col within block [0,14)

  int p  = perm[b * (G * G) + si * G + sj];
  int oi = p >> 2;          // G == 4
  int oj = p & 3;

  int oidx = (bc * H + oi * BH + y) * W4 + oj * BW4 + x4;
  out[oidx] = x[idx];
}

extern "C" void kernel_launch(void* const* d_in, const int* in_sizes, int n_in,
                              void* d_out, int out_size, void* d_ws, size_t ws_size,
                              hipStream_t stream) {
  const float4* x = (const float4*)d_in[0];
  const int* perm = (const int*)d_in[1];
  float4* out = (float4*)d_out;

  constexpr int kBlock = 256;
  constexpr int kGrid = (TOTAL4 + kBlock - 1) / kBlock; // 100,352 blocks
  block_shuffle_kernel<<<kGrid, kBlock, 0, stream>>>(x, perm, out);
}